// Round 5
// baseline (415.317 us; speedup 1.0000x reference)
//
#include <hip/hip_runtime.h>
#include <math.h>

// Problem constants (fixed by reference)
#define BATCH 4096
#define LNUM  4
#define NEIGH 32
#define FEAT  256
#define EMB   128
#define NODES 100000

// ---------------------------------------------------------------------------
// K0: convert features fp32 -> bf16 (RNE). Pure streaming, 153 MB.
// 25.6M elements, 8 per thread -> 12500 blocks x 256.
// ---------------------------------------------------------------------------
__device__ __forceinline__ unsigned int f2bf(float x) {
  unsigned int u = __float_as_uint(x);
  return (u + 0x7fffu + ((u >> 16) & 1u)) >> 16;
}

__global__ __launch_bounds__(256) void k_convert(
    const float* __restrict__ f, unsigned short* __restrict__ fb) {
  size_t i0 = ((size_t)blockIdx.x * 256 + threadIdx.x) * 8;
  float4 a = *(const float4*)(f + i0);
  float4 b = *(const float4*)(f + i0 + 4);
  uint4 o;
  o.x = f2bf(a.x) | (f2bf(a.y) << 16);
  o.y = f2bf(a.z) | (f2bf(a.w) << 16);
  o.z = f2bf(b.x) | (f2bf(b.y) << 16);
  o.w = f2bf(b.z) | (f2bf(b.w) << 16);
  *(uint4*)(fb + i0) = o;
}

// ---------------------------------------------------------------------------
// K12: gather+sum (bf16 rows, 512 B each) + h-GEMM for 32 batches x 1 layer.
// Grid (128, 4). W[l] staged through LDS in 32-row chunks -> read ONCE per
// block (64 MB total vs 512 MB in the fused-B4 version).
// sS padded to 260 floats/row: P2 row-parallel reads land on distinct banks.
// LDS: sS 33.3 KB + sW 16 KB = 49.3 KB -> 3 blocks/CU cap, grid gives 2/CU.
// ---------------------------------------------------------------------------
__global__ __launch_bounds__(256, 2) void k12(
    const int* __restrict__ neighs, const unsigned short* __restrict__ fb,
    const float* __restrict__ W, float* __restrict__ H) {
  __shared__ float sS[32][260];
  __shared__ float sW[32][128];
  int b0 = blockIdx.x * 32;
  int l = blockIdx.y;
  int tid = threadIdx.x;
  int w = tid >> 6, lane = tid & 63;

  // ---- P1: gather + neighbor-sum. Wave w owns batch-local rows w*8..w*8+7.
  int nIdx[8];
#pragma unroll
  for (int i = 0; i < 8; ++i) {
    const int* nbr = neighs + ((size_t)(b0 + w * 8 + i) * LNUM + l) * NEIGH;
    nIdx[i] = nbr[lane & 31];  // lanes 0..31 hold the 32 indices
  }
  const uint2* f2 = (const uint2*)fb;  // 8 B = 4 bf16; row = 64 uint2
#pragma unroll
  for (int i = 0; i < 8; i += 2) {
    float acc0[4] = {0.f, 0.f, 0.f, 0.f};
    float acc1[4] = {0.f, 0.f, 0.f, 0.f};
#pragma unroll
    for (int jj = 0; jj < 8; ++jj) {  // 8 loads in flight (64 lines) per step
      uint2 va[4], vb[4];
#pragma unroll
      for (int q = 0; q < 4; ++q) {
        int na = __shfl(nIdx[i], jj * 4 + q, 64);
        va[q] = f2[(size_t)na * 64 + lane];
      }
#pragma unroll
      for (int q = 0; q < 4; ++q) {
        int nb = __shfl(nIdx[i + 1], jj * 4 + q, 64);
        vb[q] = f2[(size_t)nb * 64 + lane];
      }
#pragma unroll
      for (int q = 0; q < 4; ++q) {
        acc0[0] += __uint_as_float(va[q].x << 16);
        acc0[1] += __uint_as_float(va[q].x & 0xffff0000u);
        acc0[2] += __uint_as_float(va[q].y << 16);
        acc0[3] += __uint_as_float(va[q].y & 0xffff0000u);
        acc1[0] += __uint_as_float(vb[q].x << 16);
        acc1[1] += __uint_as_float(vb[q].x & 0xffff0000u);
        acc1[2] += __uint_as_float(vb[q].y << 16);
        acc1[3] += __uint_as_float(vb[q].y & 0xffff0000u);
      }
    }
    *(float4*)&sS[w * 8 + i][lane * 4] =
        make_float4(acc0[0], acc0[1], acc0[2], acc0[3]);
    *(float4*)&sS[w * 8 + i + 1][lane * 4] =
        make_float4(acc1[0], acc1[1], acc1[2], acc1[3]);
  }
  __syncthreads();

  // ---- P2: H rows = sS rows @ W[l]; W staged through LDS once per block.
  int tx = tid & 31;   // cols tx*4..+3
  int ty = tid >> 5;   // rows ty*4..+3
  float acc[4][4] = {};
  const float* Wl = W + (size_t)l * FEAT * EMB;
  for (int k0 = 0; k0 < FEAT; k0 += 32) {
#pragma unroll
    for (int t = 0; t < 4; ++t) {   // stage 32x128 chunk (16 KB)
      int idx = tid + t * 256;      // float4 index 0..1023
      int kk = idx >> 5;
      int cc = idx & 31;
      *(float4*)&sW[kk][cc * 4] =
          *(const float4*)&Wl[(size_t)(k0 + kk) * EMB + cc * 4];
    }
    __syncthreads();
#pragma unroll
    for (int kc = 0; kc < 32; kc += 4) {
      float4 s4[4];
#pragma unroll
      for (int r = 0; r < 4; ++r)
        s4[r] = *(const float4*)&sS[ty * 4 + r][k0 + kc];
#pragma unroll
      for (int kk = 0; kk < 4; ++kk) {
        float4 wv = *(const float4*)&sW[kc + kk][tx * 4];
#pragma unroll
        for (int r = 0; r < 4; ++r) {
          float sv = ((const float*)&s4[r])[kk];
          acc[r][0] += sv * wv.x; acc[r][1] += sv * wv.y;
          acc[r][2] += sv * wv.z; acc[r][3] += sv * wv.w;
        }
      }
    }
    __syncthreads();
  }
#pragma unroll
  for (int r = 0; r < 4; ++r) {
    int b = b0 + ty * 4 + r;
    *(float4*)&H[((size_t)b * LNUM + l) * EMB + tx * 4] =
        make_float4(acc[r][0], acc[r][1], acc[r][2], acc[r][3]);
  }
}

// ---------------------------------------------------------------------------
// K34: scores + softmax + agg + out-GEMM + residual + L2-normalize for
// 16 batches (64 (b,l) rows) per block. Grid 256 x 256 threads.
// H rows live in LDS (read once). Ws1/Wt read once per wave.
// ---------------------------------------------------------------------------
__global__ __launch_bounds__(256, 2) void k34(
    const float* __restrict__ H, const float* __restrict__ Ws1,
    const float* __restrict__ Ws2, const float* __restrict__ Wt,
    const int* __restrict__ node_i, const int* __restrict__ layers,
    const float* __restrict__ layer_embs, float* __restrict__ out) {
  __shared__ float sHH[64][130];
  __shared__ float sAgg[16][128];
  __shared__ float sc[64];
  int b0 = blockIdx.x * 16;
  int tid = threadIdx.x;
  int w = tid >> 6, lane = tid & 63;

  // stage H rows for 16 batches: 64 x 128 floats, coalesced
  {
    const float4* Hp = (const float4*)(H + (size_t)b0 * LNUM * EMB);
    for (int i = tid; i < 64 * 32; i += 256) {
      int r = i >> 5, c = i & 31;
      *(float4*)&sHH[r][c * 4] = Hp[i];
    }
  }
  __syncthreads();

  // ---- P3: sc[r] = tanh(sHH[r] @ Ws1) @ Ws2; wave w rows w*16..w*16+15
  {
    float acc[16][2] = {};
    for (int k = 0; k < EMB; k += 2) {
      float2 h2[16];
#pragma unroll
      for (int r = 0; r < 16; ++r)
        h2[r] = *(const float2*)&sHH[w * 16 + r][k];  // wave-uniform: bcast
      float2 w0 = *(const float2*)&Ws1[(size_t)k * EMB + lane * 2];
      float2 w1 = *(const float2*)&Ws1[(size_t)(k + 1) * EMB + lane * 2];
#pragma unroll
      for (int r = 0; r < 16; ++r) {
        acc[r][0] += h2[r].x * w0.x + h2[r].y * w1.x;
        acc[r][1] += h2[r].x * w0.y + h2[r].y * w1.y;
      }
    }
    float2 w2v = *(const float2*)&Ws2[lane * 2];
#pragma unroll
    for (int r = 0; r < 16; ++r) {
      float p = tanhf(acc[r][0]) * w2v.x + tanhf(acc[r][1]) * w2v.y;
#pragma unroll
      for (int m = 1; m < 64; m <<= 1) p += __shfl_xor(p, m, 64);
      if (lane == 0) sc[w * 16 + r] = p;
    }
  }
  __syncthreads();

  // ---- P4a: softmax over layers + attention-weighted aggregation
  for (int i = tid; i < 16 * EMB; i += 256) {
    int lb = i >> 7, m = i & 127;
    float s0 = sc[lb * 4 + 0], s1 = sc[lb * 4 + 1];
    float s2 = sc[lb * 4 + 2], s3 = sc[lb * 4 + 3];
    float mx = fmaxf(fmaxf(s0, s1), fmaxf(s2, s3));
    float e0 = expf(s0 - mx), e1 = expf(s1 - mx);
    float e2 = expf(s2 - mx), e3 = expf(s3 - mx);
    float inv = 1.0f / (e0 + e1 + e2 + e3);
    float a = e0 * sHH[lb * 4 + 0][m] + e1 * sHH[lb * 4 + 1][m] +
              e2 * sHH[lb * 4 + 2][m] + e3 * sHH[lb * 4 + 3][m];
    sAgg[lb][m] = a * inv;
  }
  __syncthreads();

  // ---- P4b: wave w -> local batches w*4..w*4+3; Wt read once per wave
  {
    float ax[4] = {0.f, 0.f, 0.f, 0.f}, ay[4] = {0.f, 0.f, 0.f, 0.f};
    for (int k = 0; k < EMB; ++k) {
      float2 wv = *(const float2*)&Wt[(size_t)k * EMB + lane * 2];
#pragma unroll
      for (int g = 0; g < 4; ++g) {
        float a = sAgg[w * 4 + g][k];  // wave-uniform: bcast
        ax[g] += a * wv.x;
        ay[g] += a * wv.y;
      }
    }
#pragma unroll
    for (int g = 0; g < 4; ++g) {
      int b = b0 + w * 4 + g;
      int node = node_i[b];
      int lay = layers[b];
      float2 e = *(const float2*)&layer_embs[((size_t)node * LNUM + lay) * EMB +
                                             lane * 2];
      float vx = ax[g] + e.x, vy = ay[g] + e.y;
      float ss = vx * vx + vy * vy;
#pragma unroll
      for (int m = 1; m < 64; m <<= 1) ss += __shfl_xor(ss, m, 64);
      float inv = 1.0f / fmaxf(sqrtf(ss), 1e-12f);
      *(float2*)&out[(size_t)b * EMB + lane * 2] =
          make_float2(vx * inv, vy * inv);
    }
  }
}

extern "C" void kernel_launch(void* const* d_in, const int* in_sizes, int n_in,
                              void* d_out, int out_size, void* d_ws,
                              size_t ws_size, hipStream_t stream) {
  const int* layers = (const int*)d_in[0];
  const int* node_i = (const int*)d_in[1];
  const int* neighs = (const int*)d_in[2];
  const float* features = (const float*)d_in[3];
  const float* layer_embs = (const float*)d_in[4];
  const float* neigh_emb_trans = (const float*)d_in[5];
  const float* trans_weights = (const float*)d_in[6];
  const float* trans_weights_s1 = (const float*)d_in[7];
  const float* trans_weights_s2 = (const float*)d_in[8];
  float* out = (float*)d_out;

  // ws layout: fb (bf16 features, 51.2 MB) | H (16384x128 fp32, 8.4 MB)
  unsigned short* fb = (unsigned short*)d_ws;
  float* H = (float*)((char*)d_ws + (size_t)NODES * FEAT * sizeof(unsigned short));

  k_convert<<<dim3(NODES * FEAT / (256 * 8)), 256, 0, stream>>>(features, fb);
  k12<<<dim3(BATCH / 32, LNUM), 256, 0, stream>>>(neighs, fb, neigh_emb_trans, H);
  k34<<<dim3(BATCH / 16), 256, 0, stream>>>(H, trans_weights_s1,
                                            trans_weights_s2, trans_weights,
                                            node_i, layers, layer_embs, out);
}

// Round 6
// 414.826 us; speedup vs baseline: 1.0012x; 1.0012x over previous
//
#include <hip/hip_runtime.h>
#include <math.h>

// Problem constants (fixed by reference)
#define BATCH 4096
#define LNUM  4
#define NEIGH 32
#define FEAT  256
#define EMB   128
#define NODES 100000

// ---------------------------------------------------------------------------
// K0: convert features fp32 -> bf16 (RNE). Pure streaming, 153 MB.
// ---------------------------------------------------------------------------
__device__ __forceinline__ unsigned int f2bf(float x) {
  unsigned int u = __float_as_uint(x);
  return (u + 0x7fffu + ((u >> 16) & 1u)) >> 16;
}

__global__ __launch_bounds__(256) void k_convert(
    const float* __restrict__ f, unsigned short* __restrict__ fb) {
  size_t i0 = ((size_t)blockIdx.x * 256 + threadIdx.x) * 8;
  float4 a = *(const float4*)(f + i0);
  float4 b = *(const float4*)(f + i0 + 4);
  uint4 o;
  o.x = f2bf(a.x) | (f2bf(a.y) << 16);
  o.y = f2bf(a.z) | (f2bf(a.w) << 16);
  o.z = f2bf(b.x) | (f2bf(b.y) << 16);
  o.w = f2bf(b.z) | (f2bf(b.w) << 16);
  *(uint4*)(fb + i0) = o;
}

// ---------------------------------------------------------------------------
// K12: gather+sum + h-GEMM for 32 batches x 1 layer. Grid (128, 4).
// P1: PAIRED-ROW gather — one dwordx4 wave-instruction (1 KB) covers TWO
// 512-B bf16 rows (half-wave each): 256K gather instructions total (2x fewer
// than R5). Rationale: measured gather rate is ~const per wave-instruction.
// P2: W[l] staged through LDS once per block (64 MB total W traffic).
// LDS: sS 33.3 KB + sW 16 KB -> 2 blocks/CU (grid-limited).
// ---------------------------------------------------------------------------
__global__ __launch_bounds__(256, 2) void k12(
    const int* __restrict__ neighs, const unsigned short* __restrict__ fb,
    const float* __restrict__ W, float* __restrict__ H) {
  __shared__ float sS[32][260];
  __shared__ float sW[32][128];
  int b0 = blockIdx.x * 32;
  int l = blockIdx.y;
  int tid = threadIdx.x;
  int w = tid >> 6, lane = tid & 63;
  int half = lane >> 5;      // 0: row A, 1: row B of each pair
  int seg = lane & 31;       // 16-B segment within the 512-B row

  // ---- P1: wave w owns rows w*8 .. w*8+7 (4 pairs) ----------------------
  int idx[8];
#pragma unroll
  for (int i = 0; i < 8; ++i) {
    const int* nbr = neighs + ((size_t)(b0 + w * 8 + i) * LNUM + l) * NEIGH;
    idx[i] = nbr[seg];  // lanes 0..31 hold the 32 indices (dup in upper half)
  }
#pragma unroll
  for (int p = 0; p < 4; ++p) {
    float a[8] = {0.f, 0.f, 0.f, 0.f, 0.f, 0.f, 0.f, 0.f};
#pragma unroll
    for (int jj = 0; jj < 4; ++jj) {  // 8 paired loads in flight per step
      uint4 v[8];
#pragma unroll
      for (int q = 0; q < 8; ++q) {
        int j = jj * 8 + q;
        int nA = __shfl(idx[2 * p], j, 64);      // uniform
        int nB = __shfl(idx[2 * p + 1], j, 64);  // uniform
        int n = half ? nB : nA;                  // per-half row select
        v[q] = *((const uint4*)(fb + (size_t)n * FEAT) + seg);
      }
#pragma unroll
      for (int q = 0; q < 8; ++q) {
        a[0] += __uint_as_float(v[q].x << 16);
        a[1] += __uint_as_float(v[q].x & 0xffff0000u);
        a[2] += __uint_as_float(v[q].y << 16);
        a[3] += __uint_as_float(v[q].y & 0xffff0000u);
        a[4] += __uint_as_float(v[q].z << 16);
        a[5] += __uint_as_float(v[q].z & 0xffff0000u);
        a[6] += __uint_as_float(v[q].w << 16);
        a[7] += __uint_as_float(v[q].w & 0xffff0000u);
      }
    }
    int r = w * 8 + 2 * p + half;
    *(float4*)&sS[r][seg * 8] = make_float4(a[0], a[1], a[2], a[3]);
    *(float4*)&sS[r][seg * 8 + 4] = make_float4(a[4], a[5], a[6], a[7]);
  }
  __syncthreads();

  // ---- P2: H rows = sS rows @ W[l]; W staged through LDS once per block.
  int tx = tid & 31;   // cols tx*4..+3
  int ty = tid >> 5;   // rows ty*4..+3
  float acc[4][4] = {};
  const float* Wl = W + (size_t)l * FEAT * EMB;
  for (int k0 = 0; k0 < FEAT; k0 += 32) {
#pragma unroll
    for (int t = 0; t < 4; ++t) {   // stage 32x128 chunk (16 KB)
      int i2 = tid + t * 256;       // float4 index 0..1023
      int kk = i2 >> 5;
      int cc = i2 & 31;
      *(float4*)&sW[kk][cc * 4] =
          *(const float4*)&Wl[(size_t)(k0 + kk) * EMB + cc * 4];
    }
    __syncthreads();
#pragma unroll
    for (int kc = 0; kc < 32; kc += 4) {
      float4 s4[4];
#pragma unroll
      for (int r = 0; r < 4; ++r)
        s4[r] = *(const float4*)&sS[ty * 4 + r][k0 + kc];
#pragma unroll
      for (int kk = 0; kk < 4; ++kk) {
        float4 wv = *(const float4*)&sW[kc + kk][tx * 4];
#pragma unroll
        for (int r = 0; r < 4; ++r) {
          float sv = ((const float*)&s4[r])[kk];
          acc[r][0] += sv * wv.x; acc[r][1] += sv * wv.y;
          acc[r][2] += sv * wv.z; acc[r][3] += sv * wv.w;
        }
      }
    }
    __syncthreads();
  }
#pragma unroll
  for (int r = 0; r < 4; ++r) {
    int b = b0 + ty * 4 + r;
    *(float4*)&H[((size_t)b * LNUM + l) * EMB + tx * 4] =
        make_float4(acc[r][0], acc[r][1], acc[r][2], acc[r][3]);
  }
}

// ---------------------------------------------------------------------------
// K34: scores + softmax + agg + out-GEMM + residual + L2-normalize for
// 16 batches (64 (b,l) rows) per block. Grid 256 x 256 threads.
// ---------------------------------------------------------------------------
__global__ __launch_bounds__(256, 2) void k34(
    const float* __restrict__ H, const float* __restrict__ Ws1,
    const float* __restrict__ Ws2, const float* __restrict__ Wt,
    const int* __restrict__ node_i, const int* __restrict__ layers,
    const float* __restrict__ layer_embs, float* __restrict__ out) {
  __shared__ float sHH[64][130];
  __shared__ float sAgg[16][128];
  __shared__ float sc[64];
  int b0 = blockIdx.x * 16;
  int tid = threadIdx.x;
  int w = tid >> 6, lane = tid & 63;

  {
    const float4* Hp = (const float4*)(H + (size_t)b0 * LNUM * EMB);
    for (int i = tid; i < 64 * 32; i += 256) {
      int r = i >> 5, c = i & 31;
      *(float4*)&sHH[r][c * 4] = Hp[i];
    }
  }
  __syncthreads();

  // ---- P3: sc[r] = tanh(sHH[r] @ Ws1) @ Ws2; wave w rows w*16..w*16+15
  {
    float acc[16][2] = {};
    for (int k = 0; k < EMB; k += 2) {
      float2 h2[16];
#pragma unroll
      for (int r = 0; r < 16; ++r)
        h2[r] = *(const float2*)&sHH[w * 16 + r][k];  // wave-uniform: bcast
      float2 w0 = *(const float2*)&Ws1[(size_t)k * EMB + lane * 2];
      float2 w1 = *(const float2*)&Ws1[(size_t)(k + 1) * EMB + lane * 2];
#pragma unroll
      for (int r = 0; r < 16; ++r) {
        acc[r][0] += h2[r].x * w0.x + h2[r].y * w1.x;
        acc[r][1] += h2[r].x * w0.y + h2[r].y * w1.y;
      }
    }
    float2 w2v = *(const float2*)&Ws2[lane * 2];
#pragma unroll
    for (int r = 0; r < 16; ++r) {
      float p = tanhf(acc[r][0]) * w2v.x + tanhf(acc[r][1]) * w2v.y;
#pragma unroll
      for (int m = 1; m < 64; m <<= 1) p += __shfl_xor(p, m, 64);
      if (lane == 0) sc[w * 16 + r] = p;
    }
  }
  __syncthreads();

  // ---- P4a: softmax over layers + attention-weighted aggregation
  for (int i = tid; i < 16 * EMB; i += 256) {
    int lb = i >> 7, m = i & 127;
    float s0 = sc[lb * 4 + 0], s1 = sc[lb * 4 + 1];
    float s2 = sc[lb * 4 + 2], s3 = sc[lb * 4 + 3];
    float mx = fmaxf(fmaxf(s0, s1), fmaxf(s2, s3));
    float e0 = expf(s0 - mx), e1 = expf(s1 - mx);
    float e2 = expf(s2 - mx), e3 = expf(s3 - mx);
    float inv = 1.0f / (e0 + e1 + e2 + e3);
    float a = e0 * sHH[lb * 4 + 0][m] + e1 * sHH[lb * 4 + 1][m] +
              e2 * sHH[lb * 4 + 2][m] + e3 * sHH[lb * 4 + 3][m];
    sAgg[lb][m] = a * inv;
  }
  __syncthreads();

  // ---- P4b: wave w -> local batches w*4..w*4+3; Wt read once per wave
  {
    float ax[4] = {0.f, 0.f, 0.f, 0.f}, ay[4] = {0.f, 0.f, 0.f, 0.f};
    for (int k = 0; k < EMB; ++k) {
      float2 wv = *(const float2*)&Wt[(size_t)k * EMB + lane * 2];
#pragma unroll
      for (int g = 0; g < 4; ++g) {
        float a = sAgg[w * 4 + g][k];  // wave-uniform: bcast
        ax[g] += a * wv.x;
        ay[g] += a * wv.y;
      }
    }
#pragma unroll
    for (int g = 0; g < 4; ++g) {
      int b = b0 + w * 4 + g;
      int node = node_i[b];
      int lay = layers[b];
      float2 e = *(const float2*)&layer_embs[((size_t)node * LNUM + lay) * EMB +
                                             lane * 2];
      float vx = ax[g] + e.x, vy = ay[g] + e.y;
      float ss = vx * vx + vy * vy;
#pragma unroll
      for (int m = 1; m < 64; m <<= 1) ss += __shfl_xor(ss, m, 64);
      float inv = 1.0f / fmaxf(sqrtf(ss), 1e-12f);
      *(float2*)&out[(size_t)b * EMB + lane * 2] =
          make_float2(vx * inv, vy * inv);
    }
  }
}

extern "C" void kernel_launch(void* const* d_in, const int* in_sizes, int n_in,
                              void* d_out, int out_size, void* d_ws,
                              size_t ws_size, hipStream_t stream) {
  const int* layers = (const int*)d_in[0];
  const int* node_i = (const int*)d_in[1];
  const int* neighs = (const int*)d_in[2];
  const float* features = (const float*)d_in[3];
  const float* layer_embs = (const float*)d_in[4];
  const float* neigh_emb_trans = (const float*)d_in[5];
  const float* trans_weights = (const float*)d_in[6];
  const float* trans_weights_s1 = (const float*)d_in[7];
  const float* trans_weights_s2 = (const float*)d_in[8];
  float* out = (float*)d_out;

  // ws layout: fb (bf16 features, 51.2 MB) | H (16384x128 fp32, 8.4 MB)
  unsigned short* fb = (unsigned short*)d_ws;
  float* H = (float*)((char*)d_ws + (size_t)NODES * FEAT * sizeof(unsigned short));

  k_convert<<<dim3(NODES * FEAT / (256 * 8)), 256, 0, stream>>>(features, fb);
  k12<<<dim3(BATCH / 32, LNUM), 256, 0, stream>>>(neighs, fb, neigh_emb_trans, H);
  k34<<<dim3(BATCH / 16), 256, 0, stream>>>(H, trans_weights_s1,
                                            trans_weights_s2, trans_weights,
                                            node_i, layers, layer_embs, out);
}